// Round 4
// baseline (218.859 us; speedup 1.0000x reference)
//
#include <hip/hip_runtime.h>
#include <hip/hip_bf16.h>

constexpr int NB = 8;      // batch
constexpr int T  = 2048;   // seq
constexpr int C  = 1024;   // embed
constexpr int Hd = 128;    // head size

typedef short bf16x8 __attribute__((ext_vector_type(8)));
typedef float floatx4 __attribute__((ext_vector_type(4)));

__device__ __forceinline__ ushort f2bf(float x) {
    return __builtin_bit_cast(ushort, __float2bfloat16(x));
}
__device__ __forceinline__ float bf2f(ushort u) {
    unsigned int x = ((unsigned int)u) << 16;
    return __builtin_bit_cast(float, x);
}
__device__ __forceinline__ void async16(ushort* lds, const ushort* g) {
    __builtin_amdgcn_global_load_lds(
        (const __attribute__((address_space(1))) unsigned int*)g,
        (__attribute__((address_space(3))) unsigned int*)lds, 16, 0, 0);
}

// ---------------------------------------------------------------------------
// Kernel 1: fused fp32->bf16 convert for X and stacked W (Wq scaled).
// ---------------------------------------------------------------------------
__global__ __launch_bounds__(256) void convert_xw(
    const float* __restrict__ X, const float* __restrict__ Wq,
    const float* __restrict__ Wk, const float* __restrict__ Wv,
    ushort* __restrict__ Xb, ushort* __restrict__ Wb)
{
    int bid = blockIdx.x;
    if (bid < 8192) {
        size_t i = ((size_t)bid * 256 + threadIdx.x) * 8;
        float4 a = *(const float4*)&X[i];
        float4 b = *(const float4*)&X[i + 4];
        bf16x8 o;
        o[0] = (short)f2bf(a.x); o[1] = (short)f2bf(a.y);
        o[2] = (short)f2bf(a.z); o[3] = (short)f2bf(a.w);
        o[4] = (short)f2bf(b.x); o[5] = (short)f2bf(b.y);
        o[6] = (short)f2bf(b.z); o[7] = (short)f2bf(b.w);
        *(bf16x8*)&Xb[i] = o;
    } else {
        int g = (bid - 8192) * 256 + threadIdx.x;      // 0..49151
        size_t base = (size_t)g * 8;
        int sel = (int)(base >> 17);                   // which W
        const float* W = sel == 0 ? Wq : (sel == 1 ? Wk : Wv);
        float s = (sel == 0) ? 0.12751744f : 1.0f;     // log2e/sqrt(128) in Wq
        size_t off = base - (size_t)sel * 131072;
        float4 a = *(const float4*)&W[off];
        float4 b = *(const float4*)&W[off + 4];
        bf16x8 o;
        o[0] = (short)f2bf(a.x * s); o[1] = (short)f2bf(a.y * s);
        o[2] = (short)f2bf(a.z * s); o[3] = (short)f2bf(a.w * s);
        o[4] = (short)f2bf(b.x * s); o[5] = (short)f2bf(b.y * s);
        o[6] = (short)f2bf(b.z * s); o[7] = (short)f2bf(b.w * s);
        *(bf16x8*)&Wb[base] = o;
    }
}

// ---------------------------------------------------------------------------
// Kernel 2: QKV GEMM bf16, BM=128 BN=128 BK=64, global_load_lds + XOR swizzle.
// blockIdx.y = 0/1/2 -> Q/K/V. V is transposed through LDS in the epilogue
// and written directly as Vt[b][h][t] (no separate transpose kernel).
// ---------------------------------------------------------------------------
__global__ __launch_bounds__(256) void qkv_gemm(
    const ushort* __restrict__ Xb, const ushort* __restrict__ Wb,
    ushort* __restrict__ Qo, ushort* __restrict__ Ko, ushort* __restrict__ Vt)
{
    __shared__ ushort SM[128 * 130];      // 33.3KB; Al/Bl overlay + Cl for transpose
    ushort* Al = SM;                      // 128x64
    ushort* Bl = SM + 8192;               // 128x64
    const int m0 = blockIdx.x * 128;
    const int n0 = blockIdx.y * 128;      // row offset into stacked Wb
    const int tid = threadIdx.x, lane = tid & 63, wave = tid >> 6;
    const int quad = lane >> 4, colL = lane & 15;
    const int wm = (wave & 1) * 64, wn = (wave >> 1) * 64;
    const int lr = lane >> 3;
    const int lcs = ((lane & 7) ^ (lr & 7)) * 8;   // swizzled source column

    floatx4 acc[4][4] = {};

    for (int k0 = 0; k0 < C; k0 += 64) {
        for (int t = 0; t < 4; ++t) {
            int q = wave * 4 + t;
            async16(&Al[q * 512 + lane * 8],
                    &Xb[(size_t)(m0 + q * 8 + lr) * C + k0 + lcs]);
        }
        for (int t = 0; t < 4; ++t) {
            int q = wave * 4 + t;
            async16(&Bl[q * 512 + lane * 8],
                    &Wb[(size_t)(n0 + q * 8 + lr) * C + k0 + lcs]);
        }
        __syncthreads();

        bf16x8 af[2][4], bfr[2][4];
        for (int kk = 0; kk < 2; ++kk) {
            for (int mt = 0; mt < 4; ++mt)
                af[kk][mt] = *(const bf16x8*)
                    &Al[(wm + mt * 16 + colL) * 64 + (((kk * 4 + quad) ^ (colL & 7))) * 8];
            for (int nt = 0; nt < 4; ++nt)
                bfr[kk][nt] = *(const bf16x8*)
                    &Bl[(wn + nt * 16 + colL) * 64 + (((kk * 4 + quad) ^ (colL & 7))) * 8];
        }
        for (int kk = 0; kk < 2; ++kk)
            for (int mt = 0; mt < 4; ++mt)
                for (int nt = 0; nt < 4; ++nt)
                    acc[mt][nt] = __builtin_amdgcn_mfma_f32_16x16x32_bf16(
                        af[kk][mt], bfr[kk][nt], acc[mt][nt], 0, 0, 0);
        __syncthreads();
    }

    const int sel = blockIdx.y;
    if (sel < 2) {
        ushort* dst = sel == 0 ? Qo : Ko;
        for (int mt = 0; mt < 4; ++mt)
            for (int nt = 0; nt < 4; ++nt)
                for (int r = 0; r < 4; ++r) {
                    int row = m0 + wm + mt * 16 + quad * 4 + r;
                    int h = wn + nt * 16 + colL;
                    dst[(size_t)row * Hd + h] = f2bf(acc[mt][nt][r]);
                }
    } else {
        // V: transpose 128x128 tile through LDS (stride 130 = odd words -> no
        // conflicts on column reads), write Vt[b][h][t] coalesced.
        for (int mt = 0; mt < 4; ++mt)
            for (int nt = 0; nt < 4; ++nt)
                for (int r = 0; r < 4; ++r)
                    SM[(wm + mt * 16 + quad * 4 + r) * 130 + wn + nt * 16 + colL] =
                        f2bf(acc[mt][nt][r]);
        __syncthreads();
        const int b = m0 >> 11, tb = m0 & 2047;
        const int h = tid >> 1, half = tid & 1;
        for (int ch = 0; ch < 8; ++ch) {
            int t0 = half * 64 + ch * 8;
            bf16x8 o;
            for (int jx = 0; jx < 8; ++jx)
                o[jx] = (short)SM[(t0 + jx) * 130 + h];
            *(bf16x8*)&Vt[((size_t)b * Hd + h) * T + tb + t0] = o;
        }
    }
}

// ---------------------------------------------------------------------------
// Kernel 3: barrier-free split-K causal flash attention.
// Wave = 16 q-rows (tile jj in [0,128) per batch) x 256-key chunk c.
// Block = 4 waves with SAME chunk c and 4 consecutive jj (shared K/V lines ->
// L1 broadcast). K and Vt fragments read DIRECTLY from global (L2-resident).
// LDS: only per-wave P scratch. No __syncthreads at all.
// Per batch: group g = jj>>4 has chunks c in [0,g]; blocks per group 4(g+1);
// blocks per batch 144; slots per batch 576.
// ---------------------------------------------------------------------------
__global__ __launch_bounds__(256, 4) void attn_partial(
    const ushort* __restrict__ Q, const ushort* __restrict__ Kg,
    const ushort* __restrict__ Vt, ushort* __restrict__ Opart,
    float* __restrict__ mpart, float* __restrict__ lpart)
{
    __shared__ ushort Pl[4][16 * 72];     // per-wave P scratch (2304B each)

    const int tid = threadIdx.x, lane = tid & 63, wave = tid >> 6;
    const int quad = lane >> 4, colL = lane & 15;

    // decode block -> (b, g, c, jj)
    int bb = blockIdx.x;                  // 0..1151
    int b = bb / 144;
    int r0 = bb - b * 144;
    int g = 0;
    while (2 * (g + 1) * (g + 2) <= r0) ++g;         // g in 0..7
    int r = r0 - 2 * g * (g + 1);                    // 0..4(g+1)-1
    int c = r >> 2;
    int jj = 16 * g + (r & 3) * 4 + wave;            // this wave's q-tile

    const int kmax = jj * 16 + 16;
    int len = kmax - 256 * c; if (len > 256) len = 256;
    const int niter = (len + 63) >> 6;               // 1..4
    const bool diagchunk = (c == g);

    // Q fragments (A-layout), resident all iterations
    bf16x8 qa[4];
    {
        const ushort* qp = &Q[(size_t)(b * T + jj * 16 + colL) * Hd + quad * 8];
        for (int ks = 0; ks < 4; ++ks)
            qa[ks] = *(const bf16x8*)&qp[ks * 32];
    }

    float m_r[4], l_r[4];
    for (int rr = 0; rr < 4; ++rr) { m_r[rr] = -__builtin_inff(); l_r[rr] = 0.f; }
    floatx4 Oacc[8] = {};
    ushort* Pw = Pl[wave];

    for (int it = 0; it < niter; ++it) {
        const int k0 = 256 * c + 64 * it;

        // S = Q K^T; K fragments straight from global (B-layout == 16B of a K row)
        floatx4 accS[4] = {};
        const ushort* kf = &Kg[((size_t)b * T + k0 + colL) * Hd + quad * 8];
        for (int nt = 0; nt < 4; ++nt) {
            bf16x8 kb0 = *(const bf16x8*)&kf[nt * 16 * Hd];
            bf16x8 kb1 = *(const bf16x8*)&kf[nt * 16 * Hd + 32];
            bf16x8 kb2 = *(const bf16x8*)&kf[nt * 16 * Hd + 64];
            bf16x8 kb3 = *(const bf16x8*)&kf[nt * 16 * Hd + 96];
            accS[nt] = __builtin_amdgcn_mfma_f32_16x16x32_bf16(qa[0], kb0, accS[nt], 0, 0, 0);
            accS[nt] = __builtin_amdgcn_mfma_f32_16x16x32_bf16(qa[1], kb1, accS[nt], 0, 0, 0);
            accS[nt] = __builtin_amdgcn_mfma_f32_16x16x32_bf16(qa[2], kb2, accS[nt], 0, 0, 0);
            accS[nt] = __builtin_amdgcn_mfma_f32_16x16x32_bf16(qa[3], kb3, accS[nt], 0, 0, 0);
        }

        // prefetch V fragments for th=0 (hide under softmax)
        const ushort* vf = &Vt[((size_t)b * Hd + colL) * T + k0 + quad * 8];
        bf16x8 vb0 = *(const bf16x8*)&vf[0];
        bf16x8 vb1 = *(const bf16x8*)&vf[32];

        if (diagchunk && it == niter - 1) {
            for (int nt = 0; nt < 4; ++nt)
                for (int rr = 0; rr < 4; ++rr) {
                    int colg = k0 + nt * 16 + colL;
                    int rowg = jj * 16 + quad * 4 + rr;
                    if (colg > rowg) accS[nt][rr] = -__builtin_inff();
                }
        }

        // online softmax (rows across the 16 colL lanes of each quad)
        float mnew[4], alpha[4], rsum[4];
        for (int rr = 0; rr < 4; ++rr) {
            float mx = fmaxf(fmaxf(accS[0][rr], accS[1][rr]),
                             fmaxf(accS[2][rr], accS[3][rr]));
            for (int off = 1; off < 16; off <<= 1)
                mx = fmaxf(mx, __shfl_xor(mx, off, 64));
            mnew[rr]  = fmaxf(m_r[rr], mx);
            alpha[rr] = __builtin_amdgcn_exp2f(m_r[rr] - mnew[rr]);
            rsum[rr]  = 0.f;
        }
        for (int nt = 0; nt < 4; ++nt)
            for (int rr = 0; rr < 4; ++rr) {
                float p = __builtin_amdgcn_exp2f(accS[nt][rr] - mnew[rr]);
                rsum[rr] += p;
                Pw[(quad * 4 + rr) * 72 + nt * 16 + colL] = f2bf(p);
            }
        for (int rr = 0; rr < 4; ++rr) {
            float s = rsum[rr];
            for (int off = 1; off < 16; off <<= 1)
                s += __shfl_xor(s, off, 64);
            l_r[rr] = l_r[rr] * alpha[rr] + s;
            m_r[rr] = mnew[rr];
        }
        for (int th = 0; th < 8; ++th)
            for (int rr = 0; rr < 4; ++rr) Oacc[th][rr] *= alpha[rr];

        // P C-layout -> A-layout via per-wave LDS (same-wave, lgkmcnt only)
        bf16x8 pa0 = *(const bf16x8*)&Pw[colL * 72 + quad * 8];
        bf16x8 pa1 = *(const bf16x8*)&Pw[colL * 72 + 32 + quad * 8];

        // O += P V^T, V fragments from global, pipelined
        for (int th = 0; th < 8; ++th) {
            bf16x8 nb0, nb1;
            if (th < 7) {
                nb0 = *(const bf16x8*)&vf[(size_t)(th + 1) * 16 * T];
                nb1 = *(const bf16x8*)&vf[(size_t)(th + 1) * 16 * T + 32];
            }
            Oacc[th] = __builtin_amdgcn_mfma_f32_16x16x32_bf16(pa0, vb0, Oacc[th], 0, 0, 0);
            Oacc[th] = __builtin_amdgcn_mfma_f32_16x16x32_bf16(pa1, vb1, Oacc[th], 0, 0, 0);
            vb0 = nb0; vb1 = nb1;
        }
    }

    // epilogue: slot = b*576 + 8g(g+1) + c*16 + (jj&15); Opart slot = [16][128]
    const int slot = b * 576 + 8 * g * (g + 1) + c * 16 + (jj & 15);
    ushort* Op = &Opart[(size_t)slot * 2048];
    for (int th = 0; th < 8; ++th)
        for (int rr = 0; rr < 4; ++rr)
            Op[(quad * 4 + rr) * 128 + th * 16 + colL] = f2bf(Oacc[th][rr]);
    if (colL == 0)
        for (int rr = 0; rr < 4; ++rr) {
            mpart[(size_t)slot * 16 + quad * 4 + rr] = m_r[rr];
            lpart[(size_t)slot * 16 + quad * 4 + rr] = l_r[rr];
        }
}

// ---------------------------------------------------------------------------
// Kernel 4: merge partials, write fp32 out. Block = (jj, b), 256 threads.
// ---------------------------------------------------------------------------
__global__ __launch_bounds__(256) void attn_combine(
    const ushort* __restrict__ Opart, const float* __restrict__ mpart,
    const float* __restrict__ lpart, float* __restrict__ out)
{
    const int jj = blockIdx.x, b = blockIdx.y;
    const int g = jj >> 4;
    const int nch = g + 1;
    const int sbase = b * 576 + 8 * g * (g + 1) + (jj & 15);   // + c*16
    const int t = threadIdx.x;
    const int row = t >> 4;
    const int cb = t & 15;

    float M = -__builtin_inff();
    for (int c = 0; c < nch; ++c)
        M = fmaxf(M, mpart[(size_t)(sbase + c * 16) * 16 + row]);
    float ltot = 0.f;
    for (int c = 0; c < nch; ++c)
        ltot += lpart[(size_t)(sbase + c * 16) * 16 + row] *
                __builtin_amdgcn_exp2f(mpart[(size_t)(sbase + c * 16) * 16 + row] - M);

    float o[8];
    for (int i = 0; i < 8; ++i) o[i] = 0.f;
    for (int c = 0; c < nch; ++c) {
        float wgt = __builtin_amdgcn_exp2f(mpart[(size_t)(sbase + c * 16) * 16 + row] - M);
        bf16x8 v = *(const bf16x8*)
            &Opart[(size_t)(sbase + c * 16) * 2048 + row * 128 + cb * 8];
        for (int i = 0; i < 8; ++i) o[i] += bf2f((ushort)v[i]) * wgt;
    }
    float inv = 1.0f / ltot;
    float* dst = &out[((size_t)(b * T) + jj * 16 + row) * Hd + cb * 8];
    for (int i = 0; i < 8; ++i) dst[i] = o[i] * inv;
}

// ---------------------------------------------------------------------------
extern "C" void kernel_launch(void* const* d_in, const int* in_sizes, int n_in,
                              void* d_out, int out_size, void* d_ws, size_t ws_size,
                              hipStream_t stream) {
    const float* x  = (const float*)d_in[0];
    const float* Wq = (const float*)d_in[1];
    const float* Wk = (const float*)d_in[2];
    const float* Wv = (const float*)d_in[3];
    float* out = (float*)d_out;

    // ws (~47 MB): Opart/mpart/lpart alias the Xb region (Xb dead after
    // qkv_gemm; attn_partial runs later on the same stream).
    char* w = (char*)d_ws;
    ushort* Xb = (ushort*)w;                                   // 33.55 MB
    ushort* Opart = (ushort*)w;                                // 18.87 MB (alias)
    float* mpart = (float*)(w + (size_t)4608 * 2048 * 2);      // 0.29 MB (alias)
    float* lpart = (float*)(w + (size_t)4608 * 2048 * 2 + 4608 * 16 * 4);
    w += (size_t)NB * T * C * 2;
    ushort* Wb  = (ushort*)w;  w += (size_t)384 * C * 2;       // 0.79 MB
    ushort* Qb  = (ushort*)w;  w += (size_t)NB * T * Hd * 2;   // 4.19 MB
    ushort* Kb  = (ushort*)w;  w += (size_t)NB * T * Hd * 2;
    ushort* Vtb = (ushort*)w;  w += (size_t)NB * T * Hd * 2;

    convert_xw<<<8384, 256, 0, stream>>>(x, Wq, Wk, Wv, Xb, Wb);
    qkv_gemm<<<dim3(128, 3), 256, 0, stream>>>(Xb, Wb, Qb, Kb, Vtb);
    attn_partial<<<1152, 256, 0, stream>>>(Qb, Kb, Vtb, Opart, mpart, lpart);
    attn_combine<<<dim3(128, 8), 256, 0, stream>>>(Opart, mpart, lpart, out);
}

// Round 5
// 174.880 us; speedup vs baseline: 1.2515x; 1.2515x over previous
//
#include <hip/hip_runtime.h>
#include <hip/hip_bf16.h>

constexpr int NB = 8;      // batch
constexpr int T  = 2048;   // seq
constexpr int C  = 1024;   // embed
constexpr int Hd = 128;    // head size

typedef short bf16x8 __attribute__((ext_vector_type(8)));
typedef float floatx4 __attribute__((ext_vector_type(4)));

__device__ __forceinline__ ushort f2bf(float x) {
    return __builtin_bit_cast(ushort, __float2bfloat16(x));
}
__device__ __forceinline__ float bf2f(ushort u) {
    unsigned int x = ((unsigned int)u) << 16;
    return __builtin_bit_cast(float, x);
}
__device__ __forceinline__ void async16(ushort* lds, const ushort* g) {
    __builtin_amdgcn_global_load_lds(
        (const __attribute__((address_space(1))) unsigned int*)g,
        (__attribute__((address_space(3))) unsigned int*)lds, 16, 0, 0);
}

// ---------------------------------------------------------------------------
// Kernel 1: fused fp32->bf16 convert for X and stacked W (Wq scaled).
// ---------------------------------------------------------------------------
__global__ __launch_bounds__(256) void convert_xw(
    const float* __restrict__ X, const float* __restrict__ Wq,
    const float* __restrict__ Wk, const float* __restrict__ Wv,
    ushort* __restrict__ Xb, ushort* __restrict__ Wb)
{
    int bid = blockIdx.x;
    if (bid < 8192) {
        size_t i = ((size_t)bid * 256 + threadIdx.x) * 8;
        float4 a = *(const float4*)&X[i];
        float4 b = *(const float4*)&X[i + 4];
        bf16x8 o;
        o[0] = (short)f2bf(a.x); o[1] = (short)f2bf(a.y);
        o[2] = (short)f2bf(a.z); o[3] = (short)f2bf(a.w);
        o[4] = (short)f2bf(b.x); o[5] = (short)f2bf(b.y);
        o[6] = (short)f2bf(b.z); o[7] = (short)f2bf(b.w);
        *(bf16x8*)&Xb[i] = o;
    } else {
        int g = (bid - 8192) * 256 + threadIdx.x;
        size_t base = (size_t)g * 8;
        int sel = (int)(base >> 17);
        const float* W = sel == 0 ? Wq : (sel == 1 ? Wk : Wv);
        float s = (sel == 0) ? 0.12751744f : 1.0f;     // log2e/sqrt(128) in Wq
        size_t off = base - (size_t)sel * 131072;
        float4 a = *(const float4*)&W[off];
        float4 b = *(const float4*)&W[off + 4];
        bf16x8 o;
        o[0] = (short)f2bf(a.x * s); o[1] = (short)f2bf(a.y * s);
        o[2] = (short)f2bf(a.z * s); o[3] = (short)f2bf(a.w * s);
        o[4] = (short)f2bf(b.x * s); o[5] = (short)f2bf(b.y * s);
        o[6] = (short)f2bf(b.z * s); o[7] = (short)f2bf(b.w * s);
        *(bf16x8*)&Wb[base] = o;
    }
}

// ---------------------------------------------------------------------------
// Kernel 2: QKV GEMM bf16, BM=128 BN=128 BK=64, global_load_lds + XOR swizzle.
// blockIdx.y = 0/1/2 -> Q/K/V. V transposed through LDS -> Vt[b][h][t].
// ---------------------------------------------------------------------------
__global__ __launch_bounds__(256) void qkv_gemm(
    const ushort* __restrict__ Xb, const ushort* __restrict__ Wb,
    ushort* __restrict__ Qo, ushort* __restrict__ Ko, ushort* __restrict__ Vt)
{
    __shared__ ushort SM[128 * 130];      // Al/Bl overlay + transpose scratch
    ushort* Al = SM;                      // 128x64
    ushort* Bl = SM + 8192;               // 128x64
    const int m0 = blockIdx.x * 128;
    const int n0 = blockIdx.y * 128;
    const int tid = threadIdx.x, lane = tid & 63, wave = tid >> 6;
    const int quad = lane >> 4, colL = lane & 15;
    const int wm = (wave & 1) * 64, wn = (wave >> 1) * 64;
    const int lr = lane >> 3;
    const int lcs = ((lane & 7) ^ (lr & 7)) * 8;

    floatx4 acc[4][4] = {};

    for (int k0 = 0; k0 < C; k0 += 64) {
        for (int t = 0; t < 4; ++t) {
            int q = wave * 4 + t;
            async16(&Al[q * 512 + lane * 8],
                    &Xb[(size_t)(m0 + q * 8 + lr) * C + k0 + lcs]);
        }
        for (int t = 0; t < 4; ++t) {
            int q = wave * 4 + t;
            async16(&Bl[q * 512 + lane * 8],
                    &Wb[(size_t)(n0 + q * 8 + lr) * C + k0 + lcs]);
        }
        __syncthreads();

        bf16x8 af[2][4], bfr[2][4];
        for (int kk = 0; kk < 2; ++kk) {
            for (int mt = 0; mt < 4; ++mt)
                af[kk][mt] = *(const bf16x8*)
                    &Al[(wm + mt * 16 + colL) * 64 + (((kk * 4 + quad) ^ (colL & 7))) * 8];
            for (int nt = 0; nt < 4; ++nt)
                bfr[kk][nt] = *(const bf16x8*)
                    &Bl[(wn + nt * 16 + colL) * 64 + (((kk * 4 + quad) ^ (colL & 7))) * 8];
        }
        for (int kk = 0; kk < 2; ++kk)
            for (int mt = 0; mt < 4; ++mt)
                for (int nt = 0; nt < 4; ++nt)
                    acc[mt][nt] = __builtin_amdgcn_mfma_f32_16x16x32_bf16(
                        af[kk][mt], bfr[kk][nt], acc[mt][nt], 0, 0, 0);
        __syncthreads();
    }

    const int sel = blockIdx.y;
    if (sel < 2) {
        ushort* dst = sel == 0 ? Qo : Ko;
        for (int mt = 0; mt < 4; ++mt)
            for (int nt = 0; nt < 4; ++nt)
                for (int r = 0; r < 4; ++r) {
                    int row = m0 + wm + mt * 16 + quad * 4 + r;
                    int h = wn + nt * 16 + colL;
                    dst[(size_t)row * Hd + h] = f2bf(acc[mt][nt][r]);
                }
    } else {
        for (int mt = 0; mt < 4; ++mt)
            for (int nt = 0; nt < 4; ++nt)
                for (int r = 0; r < 4; ++r)
                    SM[(wm + mt * 16 + quad * 4 + r) * 130 + wn + nt * 16 + colL] =
                        f2bf(acc[mt][nt][r]);
        __syncthreads();
        const int b = m0 >> 11, tb = m0 & 2047;
        const int h = tid >> 1, half = tid & 1;
        for (int ch = 0; ch < 8; ++ch) {
            int t0 = half * 64 + ch * 8;
            bf16x8 o;
            for (int jx = 0; jx < 8; ++jx)
                o[jx] = (short)SM[(t0 + jx) * 130 + h];
            *(bf16x8*)&Vt[((size_t)b * Hd + h) * T + tb + t0] = o;
        }
    }
}

// ---------------------------------------------------------------------------
// Kernel 3: split-K causal flash attention, fat blocks.
// Block = (b, qblock j of 128 rows, kchunk c of 128 keys), c <= j.
// 4 waves; wave owns 32 q-rows. ONE staging iteration per block -> no online
// rescale: m = rowmax, l = rowsum, O = P.V (exp2 domain).
// LDS: Kl 32KB + Vl 32KB, XOR-swizzled; P aliases Kl after QK (barrier).
// Heavy-first decode (j descending). Per batch blocks: sum(j+1) = 136.
// ---------------------------------------------------------------------------
__global__ __launch_bounds__(256, 2) void attn_partial(
    const ushort* __restrict__ Q, const ushort* __restrict__ Kg,
    const ushort* __restrict__ Vt, ushort* __restrict__ Opart,
    float* __restrict__ mpart, float* __restrict__ lpart)
{
    __shared__ ushort Kl[128 * 128];   // 32KB [key][h] swizzled; P aliases later
    __shared__ ushort Vl[128 * 128];   // 32KB [h][key] swizzled

    const int tid = threadIdx.x, lane = tid & 63, wave = tid >> 6;
    const int quad = lane >> 4, colL = lane & 15;

    // decode heavy-first: j = 15,14,...; c ascending within j
    int id = blockIdx.x;               // 0..1087
    int b = id / 136;
    int rem = id - b * 136;
    int j = 15;
    while (rem >= j + 1) { rem -= (j + 1); --j; }
    int c = rem;
    const int q0 = j * 128;
    const int k0 = c * 128;
    const bool diag = (c == j);

    // stage K [128key][128h] and Vt [128h][128key], physical chunk = src^row
    {
        int r = tid >> 4, p = tid & 15;
        for (int t = 0; t < 8; ++t) {
            int row = t * 16 + r;
            async16(&Kl[t * 2048 + tid * 8],
                    &Kg[((size_t)b * T + k0 + row) * Hd + ((p ^ (row & 15)) * 8)]);
        }
        for (int t = 0; t < 8; ++t) {
            int hrow = t * 16 + r;
            async16(&Vl[t * 2048 + tid * 8],
                    &Vt[((size_t)b * Hd + hrow) * T + k0 + ((p ^ (hrow & 15)) * 8)]);
        }
    }

    // Q A-frags for this wave's 32 rows (2 m-tiles)
    bf16x8 qa[2][4];
    for (int mi = 0; mi < 2; ++mi) {
        const ushort* qp =
            &Q[((size_t)b * T + q0 + wave * 32 + mi * 16 + colL) * Hd + quad * 8];
        for (int ks = 0; ks < 4; ++ks)
            qa[mi][ks] = *(const bf16x8*)&qp[ks * 32];
    }

    __syncthreads();   // staging drained

    // S = Q K^T : 2 m-tiles x 8 n-tiles x 4 k-steps = 64 MFMA
    floatx4 accS[2][8] = {};
    for (int ks = 0; ks < 4; ++ks)
        for (int nt = 0; nt < 8; ++nt) {
            int krow = nt * 16 + colL;
            bf16x8 kb = *(const bf16x8*)&Kl[krow * 128 + (((ks * 4 + quad) ^ colL) * 8)];
            accS[0][nt] = __builtin_amdgcn_mfma_f32_16x16x32_bf16(qa[0][ks], kb, accS[0][nt], 0, 0, 0);
            accS[1][nt] = __builtin_amdgcn_mfma_f32_16x16x32_bf16(qa[1][ks], kb, accS[1][nt], 0, 0, 0);
        }

    if (diag) {
        for (int mi = 0; mi < 2; ++mi)
            for (int nt = 0; nt < 8; ++nt)
                for (int rr = 0; rr < 4; ++rr) {
                    int lrow = wave * 32 + mi * 16 + quad * 4 + rr;
                    int lcol = nt * 16 + colL;
                    if (lcol > lrow) accS[mi][nt][rr] = -__builtin_inff();
                }
    }
    __syncthreads();   // Kl reads complete; P may alias

    // softmax (single chunk: m = rowmax, l = rowsum, no rescale)
    ushort* Pw = &Kl[wave * 4096];     // [32 rows][128 keys], col^((row&7)<<4)
    float m_r[2][4], l_r[2][4];
    for (int mi = 0; mi < 2; ++mi)
        for (int rr = 0; rr < 4; ++rr) {
            float mx = accS[mi][0][rr];
            for (int nt = 1; nt < 8; ++nt) mx = fmaxf(mx, accS[mi][nt][rr]);
            for (int off = 1; off < 16; off <<= 1)
                mx = fmaxf(mx, __shfl_xor(mx, off, 64));
            m_r[mi][rr] = mx;
            l_r[mi][rr] = 0.f;
        }
    for (int mi = 0; mi < 2; ++mi) {
        for (int nt = 0; nt < 8; ++nt)
            for (int rr = 0; rr < 4; ++rr) {
                float p = __builtin_amdgcn_exp2f(accS[mi][nt][rr] - m_r[mi][rr]);
                l_r[mi][rr] += p;
                int prow = mi * 16 + quad * 4 + rr;
                Pw[prow * 128 + ((nt * 16 + colL) ^ ((prow & 7) << 4))] = f2bf(p);
            }
        for (int rr = 0; rr < 4; ++rr) {
            float s = l_r[mi][rr];
            for (int off = 1; off < 16; off <<= 1)
                s += __shfl_xor(s, off, 64);
            l_r[mi][rr] = s;
        }
    }

    // P A-frags (same-wave LDS round-trip; compiler inserts lgkmcnt)
    bf16x8 pa[2][4];
    for (int mi = 0; mi < 2; ++mi) {
        int prow = mi * 16 + colL;
        int sw = (prow & 7) << 4;
        for (int ks = 0; ks < 4; ++ks)
            pa[mi][ks] = *(const bf16x8*)&Pw[prow * 128 + ((ks * 32 + quad * 8) ^ sw)];
    }

    // O = P V : 2 m x 8 h x 4 k = 64 MFMA
    floatx4 Oacc[2][8] = {};
    for (int ks = 0; ks < 4; ++ks)
        for (int th = 0; th < 8; ++th) {
            int hrow = th * 16 + colL;
            bf16x8 vb = *(const bf16x8*)&Vl[hrow * 128 + (((ks * 4 + quad) ^ colL) * 8)];
            Oacc[0][th] = __builtin_amdgcn_mfma_f32_16x16x32_bf16(pa[0][ks], vb, Oacc[0][th], 0, 0, 0);
            Oacc[1][th] = __builtin_amdgcn_mfma_f32_16x16x32_bf16(pa[1][ks], vb, Oacc[1][th], 0, 0, 0);
        }

    // epilogue: slot = b*136 + tri(j) + c; Opart slot = [128 rows][128 h] bf16
    const int slot = b * 136 + (j * (j + 1)) / 2 + c;
    ushort* Op = &Opart[(size_t)slot * 16384];
    for (int mi = 0; mi < 2; ++mi)
        for (int th = 0; th < 8; ++th)
            for (int rr = 0; rr < 4; ++rr) {
                int row = wave * 32 + mi * 16 + quad * 4 + rr;
                Op[row * 128 + th * 16 + colL] = f2bf(Oacc[mi][th][rr]);
            }
    if (colL == 0)
        for (int mi = 0; mi < 2; ++mi)
            for (int rr = 0; rr < 4; ++rr) {
                int row = wave * 32 + mi * 16 + quad * 4 + rr;
                mpart[(size_t)slot * 128 + row] = m_r[mi][rr];
                lpart[(size_t)slot * 128 + row] = l_r[mi][rr];
            }
}

// ---------------------------------------------------------------------------
// Kernel 4: merge partials, write fp32 out. Grid (16 j, 8 b, 2 rowhalf).
// Thread owns (row, 32-h chunk).
// ---------------------------------------------------------------------------
__global__ __launch_bounds__(256) void attn_combine(
    const ushort* __restrict__ Opart, const float* __restrict__ mpart,
    const float* __restrict__ lpart, float* __restrict__ out)
{
    const int j = blockIdx.x, b = blockIdx.y;
    const int nch = j + 1;
    const int sbase = b * 136 + (j * (j + 1)) / 2;
    const int t = threadIdx.x;
    const int row = blockIdx.z * 64 + (t >> 2);
    const int h0 = (t & 3) * 32;

    float M = -__builtin_inff();
    for (int c = 0; c < nch; ++c)
        M = fmaxf(M, mpart[(size_t)(sbase + c) * 128 + row]);
    float ltot = 0.f;
    for (int c = 0; c < nch; ++c)
        ltot += lpart[(size_t)(sbase + c) * 128 + row] *
                __builtin_amdgcn_exp2f(mpart[(size_t)(sbase + c) * 128 + row] - M);

    float o[32];
    for (int i = 0; i < 32; ++i) o[i] = 0.f;
    for (int c = 0; c < nch; ++c) {
        float wgt = __builtin_amdgcn_exp2f(mpart[(size_t)(sbase + c) * 128 + row] - M);
        const ushort* Op = &Opart[(size_t)(sbase + c) * 16384 + row * 128 + h0];
        for (int x = 0; x < 4; ++x) {
            bf16x8 v = *(const bf16x8*)&Op[x * 8];
            for (int i2 = 0; i2 < 8; ++i2)
                o[x * 8 + i2] += bf2f((ushort)v[i2]) * wgt;
        }
    }
    float inv = 1.0f / ltot;
    float* dst = &out[((size_t)(b * T) + j * 128 + row) * Hd + h0];
    for (int i = 0; i < 32; ++i) dst[i] = o[i] * inv;
}

// ---------------------------------------------------------------------------
extern "C" void kernel_launch(void* const* d_in, const int* in_sizes, int n_in,
                              void* d_out, int out_size, void* d_ws, size_t ws_size,
                              hipStream_t stream) {
    const float* x  = (const float*)d_in[0];
    const float* Wq = (const float*)d_in[1];
    const float* Wk = (const float*)d_in[2];
    const float* Wv = (const float*)d_in[3];
    float* out = (float*)d_out;

    // ws (~49.4 MB). Region A is time-shared: Xb+Wb live until qkv_gemm ends;
    // Opart/mpart/lpart (written by attn_partial, later on same stream) alias it.
    char* w = (char*)d_ws;
    ushort* Xb = (ushort*)w;                                   // 33.55 MB
    ushort* Wb = (ushort*)(w + (size_t)33554432);              // 0.79 MB
    ushort* Opart = (ushort*)w;                                // 1088*32KB = 35.65 MB
    float* mpart = (float*)(w + (size_t)35651584);             // 0.56 MB
    float* lpart = (float*)(w + (size_t)35651584 + 557056);    // 0.56 MB
    w += (size_t)35651584 + 2 * 557056;
    ushort* Qb  = (ushort*)w;  w += (size_t)NB * T * Hd * 2;   // 4.19 MB
    ushort* Kb  = (ushort*)w;  w += (size_t)NB * T * Hd * 2;
    ushort* Vtb = (ushort*)w;  w += (size_t)NB * T * Hd * 2;

    convert_xw<<<8384, 256, 0, stream>>>(x, Wq, Wk, Wv, Xb, Wb);
    qkv_gemm<<<dim3(128, 3), 256, 0, stream>>>(Xb, Wb, Qb, Kb, Vtb);
    attn_partial<<<1088, 256, 0, stream>>>(Qb, Kb, Vtb, Opart, mpart, lpart);
    attn_combine<<<dim3(16, 8, 2), 256, 0, stream>>>(Opart, mpart, lpart, out);
}

// Round 6
// 162.765 us; speedup vs baseline: 1.3446x; 1.0744x over previous
//
#include <hip/hip_runtime.h>
#include <hip/hip_bf16.h>

constexpr int NB = 8;      // batch
constexpr int T  = 2048;   // seq
constexpr int C  = 1024;   // embed
constexpr int Hd = 128;    // head size

typedef short bf16x8 __attribute__((ext_vector_type(8)));
typedef float floatx4 __attribute__((ext_vector_type(4)));

__device__ __forceinline__ ushort f2bf(float x) {
    return __builtin_bit_cast(ushort, __float2bfloat16(x));
}
__device__ __forceinline__ float bf2f(ushort u) {
    unsigned int x = ((unsigned int)u) << 16;
    return __builtin_bit_cast(float, x);
}
__device__ __forceinline__ void async16(ushort* lds, const ushort* g) {
    __builtin_amdgcn_global_load_lds(
        (const __attribute__((address_space(1))) unsigned int*)g,
        (__attribute__((address_space(3))) unsigned int*)lds, 16, 0, 0);
}

// ---------------------------------------------------------------------------
// Kernel 1: fused fp32->bf16 convert for X and stacked W (Wq scaled).
// ---------------------------------------------------------------------------
__global__ __launch_bounds__(256) void convert_xw(
    const float* __restrict__ X, const float* __restrict__ Wq,
    const float* __restrict__ Wk, const float* __restrict__ Wv,
    ushort* __restrict__ Xb, ushort* __restrict__ Wb)
{
    int bid = blockIdx.x;
    if (bid < 8192) {
        size_t i = ((size_t)bid * 256 + threadIdx.x) * 8;
        float4 a = *(const float4*)&X[i];
        float4 b = *(const float4*)&X[i + 4];
        bf16x8 o;
        o[0] = (short)f2bf(a.x); o[1] = (short)f2bf(a.y);
        o[2] = (short)f2bf(a.z); o[3] = (short)f2bf(a.w);
        o[4] = (short)f2bf(b.x); o[5] = (short)f2bf(b.y);
        o[6] = (short)f2bf(b.z); o[7] = (short)f2bf(b.w);
        *(bf16x8*)&Xb[i] = o;
    } else {
        int g = (bid - 8192) * 256 + threadIdx.x;
        size_t base = (size_t)g * 8;
        int sel = (int)(base >> 17);
        const float* W = sel == 0 ? Wq : (sel == 1 ? Wk : Wv);
        float s = (sel == 0) ? 0.12751744f : 1.0f;     // log2e/sqrt(128) in Wq
        size_t off = base - (size_t)sel * 131072;
        float4 a = *(const float4*)&W[off];
        float4 b = *(const float4*)&W[off + 4];
        bf16x8 o;
        o[0] = (short)f2bf(a.x * s); o[1] = (short)f2bf(a.y * s);
        o[2] = (short)f2bf(a.z * s); o[3] = (short)f2bf(a.w * s);
        o[4] = (short)f2bf(b.x * s); o[5] = (short)f2bf(b.y * s);
        o[6] = (short)f2bf(b.z * s); o[7] = (short)f2bf(b.w * s);
        *(bf16x8*)&Wb[base] = o;
    }
}

// ---------------------------------------------------------------------------
// Kernel 2: QKV GEMM bf16, BM=128 BN=64 BK=64, global_load_lds + XOR swizzle.
// Grid (128 m-tiles, 6 n-tiles): n0 = y*64, sel = n0>>127? -> y>>1 picks Q/K/V.
// 768 blocks = 3/CU (vs 384 = 1.5/CU at BN=128 -- under-subscription fix).
// V blocks transpose through LDS scratch (overlaid on Al/Bl) -> Vt[b][h][t].
// ---------------------------------------------------------------------------
__global__ __launch_bounds__(256) void qkv_gemm(
    const ushort* __restrict__ Xb, const ushort* __restrict__ Wb,
    ushort* __restrict__ Qo, ushort* __restrict__ Ko, ushort* __restrict__ Vt)
{
    __shared__ ushort SM[12288];          // 24KB: Al(8192) + Bl(4096); TL overlays
    ushort* Al = SM;                      // 128x64
    ushort* Bl = SM + 8192;               // 64x64
    const int m0 = blockIdx.x * 128;
    const int n0 = blockIdx.y * 64;       // row into stacked Wb [384][1024]
    const int tid = threadIdx.x, lane = tid & 63, wave = tid >> 6;
    const int quad = lane >> 4, colL = lane & 15;
    const int wm = (wave & 1) * 64, wn = (wave >> 1) * 32;
    const int lr = lane >> 3;
    const int lcs = ((lane & 7) ^ (lr & 7)) * 8;   // swizzled source column

    floatx4 acc[4][2] = {};

    for (int k0 = 0; k0 < C; k0 += 64) {
        for (int t = 0; t < 4; ++t) {
            int q = wave * 4 + t;                   // 16 chunks (A: 128x64)
            async16(&Al[q * 512 + lane * 8],
                    &Xb[(size_t)(m0 + q * 8 + lr) * C + k0 + lcs]);
        }
        for (int t = 0; t < 2; ++t) {
            int q = wave * 2 + t;                   // 8 chunks (B: 64x64)
            async16(&Bl[q * 512 + lane * 8],
                    &Wb[(size_t)(n0 + q * 8 + lr) * C + k0 + lcs]);
        }
        __syncthreads();

        bf16x8 af[2][4], bfr[2][2];
        for (int kk = 0; kk < 2; ++kk) {
            for (int mt = 0; mt < 4; ++mt)
                af[kk][mt] = *(const bf16x8*)
                    &Al[(wm + mt * 16 + colL) * 64 + (((kk * 4 + quad) ^ (colL & 7))) * 8];
            for (int nt = 0; nt < 2; ++nt)
                bfr[kk][nt] = *(const bf16x8*)
                    &Bl[(wn + nt * 16 + colL) * 64 + (((kk * 4 + quad) ^ (colL & 7))) * 8];
        }
        for (int kk = 0; kk < 2; ++kk)
            for (int mt = 0; mt < 4; ++mt)
                for (int nt = 0; nt < 2; ++nt)
                    acc[mt][nt] = __builtin_amdgcn_mfma_f32_16x16x32_bf16(
                        af[kk][mt], bfr[kk][nt], acc[mt][nt], 0, 0, 0);
        __syncthreads();
    }

    const int sel = n0 >> 7;              // 0,0,1,1,2,2
    const int h0 = n0 & 127;              // 0 or 64
    if (sel < 2) {
        ushort* dst = sel == 0 ? Qo : Ko;
        for (int mt = 0; mt < 4; ++mt)
            for (int nt = 0; nt < 2; ++nt)
                for (int r = 0; r < 4; ++r) {
                    int row = m0 + wm + mt * 16 + quad * 4 + r;
                    int h = h0 + wn + nt * 16 + colL;
                    dst[(size_t)row * Hd + h] = f2bf(acc[mt][nt][r]);
                }
    } else {
        // V: transpose 128t x 64h tile through LDS scratch TL[128][66]
        ushort* TL = SM;                  // 8448 ushorts, overlays Al/Bl
        for (int mt = 0; mt < 4; ++mt)
            for (int nt = 0; nt < 2; ++nt)
                for (int r = 0; r < 4; ++r)
                    TL[(wm + mt * 16 + quad * 4 + r) * 66 + wn + nt * 16 + colL] =
                        f2bf(acc[mt][nt][r]);
        __syncthreads();
        const int b = m0 >> 11, tb = m0 & 2047;
        const int h = tid & 63, tq = tid >> 6;     // thread: h col, 32-t strip
        for (int st = 0; st < 4; ++st) {
            int t0 = tq * 32 + st * 8;
            bf16x8 o;
            for (int jx = 0; jx < 8; ++jx)
                o[jx] = (short)TL[(t0 + jx) * 66 + h];
            *(bf16x8*)&Vt[((size_t)b * Hd + h0 + h) * T + tb + t0] = o;
        }
    }
}

// ---------------------------------------------------------------------------
// Kernel 3: split-K causal flash attention, fat blocks (unchanged from R5).
// Block = (b, qblock j of 128 rows, kchunk c of 128 keys), c <= j.
// ONE staging iteration -> no online rescale. LDS 64KB, XOR-swizzled.
// ---------------------------------------------------------------------------
__global__ __launch_bounds__(256, 2) void attn_partial(
    const ushort* __restrict__ Q, const ushort* __restrict__ Kg,
    const ushort* __restrict__ Vt, ushort* __restrict__ Opart,
    float* __restrict__ mpart, float* __restrict__ lpart)
{
    __shared__ ushort Kl[128 * 128];   // 32KB [key][h] swizzled; P aliases later
    __shared__ ushort Vl[128 * 128];   // 32KB [h][key] swizzled

    const int tid = threadIdx.x, lane = tid & 63, wave = tid >> 6;
    const int quad = lane >> 4, colL = lane & 15;

    int id = blockIdx.x;               // 0..1087, heavy-first decode
    int b = id / 136;
    int rem = id - b * 136;
    int j = 15;
    while (rem >= j + 1) { rem -= (j + 1); --j; }
    int c = rem;
    const int q0 = j * 128;
    const int k0 = c * 128;
    const bool diag = (c == j);

    {
        int r = tid >> 4, p = tid & 15;
        for (int t = 0; t < 8; ++t) {
            int row = t * 16 + r;
            async16(&Kl[t * 2048 + tid * 8],
                    &Kg[((size_t)b * T + k0 + row) * Hd + ((p ^ (row & 15)) * 8)]);
        }
        for (int t = 0; t < 8; ++t) {
            int hrow = t * 16 + r;
            async16(&Vl[t * 2048 + tid * 8],
                    &Vt[((size_t)b * Hd + hrow) * T + k0 + ((p ^ (hrow & 15)) * 8)]);
        }
    }

    bf16x8 qa[2][4];
    for (int mi = 0; mi < 2; ++mi) {
        const ushort* qp =
            &Q[((size_t)b * T + q0 + wave * 32 + mi * 16 + colL) * Hd + quad * 8];
        for (int ks = 0; ks < 4; ++ks)
            qa[mi][ks] = *(const bf16x8*)&qp[ks * 32];
    }

    __syncthreads();

    floatx4 accS[2][8] = {};
    for (int ks = 0; ks < 4; ++ks)
        for (int nt = 0; nt < 8; ++nt) {
            int krow = nt * 16 + colL;
            bf16x8 kb = *(const bf16x8*)&Kl[krow * 128 + (((ks * 4 + quad) ^ colL) * 8)];
            accS[0][nt] = __builtin_amdgcn_mfma_f32_16x16x32_bf16(qa[0][ks], kb, accS[0][nt], 0, 0, 0);
            accS[1][nt] = __builtin_amdgcn_mfma_f32_16x16x32_bf16(qa[1][ks], kb, accS[1][nt], 0, 0, 0);
        }

    if (diag) {
        for (int mi = 0; mi < 2; ++mi)
            for (int nt = 0; nt < 8; ++nt)
                for (int rr = 0; rr < 4; ++rr) {
                    int lrow = wave * 32 + mi * 16 + quad * 4 + rr;
                    int lcol = nt * 16 + colL;
                    if (lcol > lrow) accS[mi][nt][rr] = -__builtin_inff();
                }
    }
    __syncthreads();   // Kl reads complete; P may alias

    ushort* Pw = &Kl[wave * 4096];     // [32 rows][128 keys], col^((row&7)<<4)
    float m_r[2][4], l_r[2][4];
    for (int mi = 0; mi < 2; ++mi)
        for (int rr = 0; rr < 4; ++rr) {
            float mx = accS[mi][0][rr];
            for (int nt = 1; nt < 8; ++nt) mx = fmaxf(mx, accS[mi][nt][rr]);
            for (int off = 1; off < 16; off <<= 1)
                mx = fmaxf(mx, __shfl_xor(mx, off, 64));
            m_r[mi][rr] = mx;
            l_r[mi][rr] = 0.f;
        }
    for (int mi = 0; mi < 2; ++mi) {
        for (int nt = 0; nt < 8; ++nt)
            for (int rr = 0; rr < 4; ++rr) {
                float p = __builtin_amdgcn_exp2f(accS[mi][nt][rr] - m_r[mi][rr]);
                l_r[mi][rr] += p;
                int prow = mi * 16 + quad * 4 + rr;
                Pw[prow * 128 + ((nt * 16 + colL) ^ ((prow & 7) << 4))] = f2bf(p);
            }
        for (int rr = 0; rr < 4; ++rr) {
            float s = l_r[mi][rr];
            for (int off = 1; off < 16; off <<= 1)
                s += __shfl_xor(s, off, 64);
            l_r[mi][rr] = s;
        }
    }

    bf16x8 pa[2][4];
    for (int mi = 0; mi < 2; ++mi) {
        int prow = mi * 16 + colL;
        int sw = (prow & 7) << 4;
        for (int ks = 0; ks < 4; ++ks)
            pa[mi][ks] = *(const bf16x8*)&Pw[prow * 128 + ((ks * 32 + quad * 8) ^ sw)];
    }

    floatx4 Oacc[2][8] = {};
    for (int ks = 0; ks < 4; ++ks)
        for (int th = 0; th < 8; ++th) {
            int hrow = th * 16 + colL;
            bf16x8 vb = *(const bf16x8*)&Vl[hrow * 128 + (((ks * 4 + quad) ^ colL) * 8)];
            Oacc[0][th] = __builtin_amdgcn_mfma_f32_16x16x32_bf16(pa[0][ks], vb, Oacc[0][th], 0, 0, 0);
            Oacc[1][th] = __builtin_amdgcn_mfma_f32_16x16x32_bf16(pa[1][ks], vb, Oacc[1][th], 0, 0, 0);
        }

    const int slot = b * 136 + (j * (j + 1)) / 2 + c;
    ushort* Op = &Opart[(size_t)slot * 16384];
    for (int mi = 0; mi < 2; ++mi)
        for (int th = 0; th < 8; ++th)
            for (int rr = 0; rr < 4; ++rr) {
                int row = wave * 32 + mi * 16 + quad * 4 + rr;
                Op[row * 128 + th * 16 + colL] = f2bf(Oacc[mi][th][rr]);
            }
    if (colL == 0)
        for (int mi = 0; mi < 2; ++mi)
            for (int rr = 0; rr < 4; ++rr) {
                int row = wave * 32 + mi * 16 + quad * 4 + rr;
                mpart[(size_t)slot * 128 + row] = m_r[mi][rr];
                lpart[(size_t)slot * 128 + row] = l_r[mi][rr];
            }
}

// ---------------------------------------------------------------------------
// Kernel 4: merge partials, write fp32 out. Grid (16 j, 8 b, 4 rowquarter)
// = 512 blocks (2/CU). Thread owns (row, 16-h chunk).
// ---------------------------------------------------------------------------
__global__ __launch_bounds__(256) void attn_combine(
    const ushort* __restrict__ Opart, const float* __restrict__ mpart,
    const float* __restrict__ lpart, float* __restrict__ out)
{
    const int j = blockIdx.x, b = blockIdx.y;
    const int nch = j + 1;
    const int sbase = b * 136 + (j * (j + 1)) / 2;
    const int t = threadIdx.x;
    const int row = blockIdx.z * 32 + (t >> 3);
    const int h0 = (t & 7) * 16;

    float M = -__builtin_inff();
    for (int c = 0; c < nch; ++c)
        M = fmaxf(M, mpart[(size_t)(sbase + c) * 128 + row]);
    float ltot = 0.f;
    for (int c = 0; c < nch; ++c)
        ltot += lpart[(size_t)(sbase + c) * 128 + row] *
                __builtin_amdgcn_exp2f(mpart[(size_t)(sbase + c) * 128 + row] - M);

    float o[16];
    for (int i = 0; i < 16; ++i) o[i] = 0.f;
    for (int c = 0; c < nch; ++c) {
        float wgt = __builtin_amdgcn_exp2f(mpart[(size_t)(sbase + c) * 128 + row] - M);
        const ushort* Op = &Opart[(size_t)(sbase + c) * 16384 + row * 128 + h0];
        for (int x = 0; x < 2; ++x) {
            bf16x8 v = *(const bf16x8*)&Op[x * 8];
            for (int i2 = 0; i2 < 8; ++i2)
                o[x * 8 + i2] += bf2f((ushort)v[i2]) * wgt;
        }
    }
    float inv = 1.0f / ltot;
    float* dst = &out[((size_t)(b * T) + j * 128 + row) * Hd + h0];
    for (int i = 0; i < 16; ++i) dst[i] = o[i] * inv;
}

// ---------------------------------------------------------------------------
extern "C" void kernel_launch(void* const* d_in, const int* in_sizes, int n_in,
                              void* d_out, int out_size, void* d_ws, size_t ws_size,
                              hipStream_t stream) {
    const float* x  = (const float*)d_in[0];
    const float* Wq = (const float*)d_in[1];
    const float* Wk = (const float*)d_in[2];
    const float* Wv = (const float*)d_in[3];
    float* out = (float*)d_out;

    // ws (~49.4 MB). Region A time-shared: Xb+Wb live until qkv_gemm ends;
    // Opart/mpart/lpart (written later by attn_partial) alias it.
    char* w = (char*)d_ws;
    ushort* Xb = (ushort*)w;                                   // 33.55 MB
    ushort* Wb = (ushort*)(w + (size_t)33554432);              // 0.79 MB
    ushort* Opart = (ushort*)w;                                // 1088*32KB = 35.65 MB
    float* mpart = (float*)(w + (size_t)35651584);             // 0.56 MB
    float* lpart = (float*)(w + (size_t)35651584 + 557056);    // 0.56 MB
    w += (size_t)35651584 + 2 * 557056;
    ushort* Qb  = (ushort*)w;  w += (size_t)NB * T * Hd * 2;   // 4.19 MB
    ushort* Kb  = (ushort*)w;  w += (size_t)NB * T * Hd * 2;
    ushort* Vtb = (ushort*)w;  w += (size_t)NB * T * Hd * 2;

    convert_xw<<<8384, 256, 0, stream>>>(x, Wq, Wk, Wv, Xb, Wb);
    qkv_gemm<<<dim3(128, 6), 256, 0, stream>>>(Xb, Wb, Qb, Kb, Vtb);
    attn_partial<<<1088, 256, 0, stream>>>(Qb, Kb, Vtb, Opart, mpart, lpart);
    attn_combine<<<dim3(16, 8, 4), 256, 0, stream>>>(Opart, mpart, lpart, out);
}